// Round 7
// baseline (103.571 us; speedup 1.0000x reference)
//
#include <hip/hip_runtime.h>
#include <hip/hip_bf16.h>

#define Bn 64
#define Sn 1452
#define Dn 1024
#define Gn 288
#define Kn 4
#define Rn 32
#define MAXT 300
#define BMW 18            // ceil(1152/64) bitmap words

typedef float f32x4 __attribute__((ext_vector_type(4)));

// Single fused kernel.
//  - head blocks (x < nheadblk=75): in-block validity scan (rem-bitmap) + 4 gather rows.
//  - tail blocks (38... 19): streaming copy of 8 rows + att scalars.
__global__ void __launch_bounds__(256)
fused3_kernel(const float* __restrict__ hs,       // B*S*D
              const int* __restrict__ idx,        // B*G*K
              const int* __restrict__ pr,         // B*2
              const int* __restrict__ rem,        // B*R
              const int* __restrict__ attn,       // B*S
              float* __restrict__ out,            // B*T*D
              float* __restrict__ att_out,        // B*T
              int vis_end, int T, int nheadblk, int tail4, int tailrows) {
    const int x = blockIdx.x;
    const int b = blockIdx.y;
    const int tid = threadIdx.x;

    if (x >= nheadblk) {
        // ---- tail: 8 rows (32 KB) per block, 128 B/lane in flight ----
        const int c = x - nheadblk;
        if (tid < 8) {
            int tr = c * 8 + tid;
            if (tr < tailrows)
                att_out[(size_t)b * T + MAXT + tr] = (float)attn[b * Sn + vis_end + tr];
        }
        const f32x4* src = (const f32x4*)(hs + ((size_t)b * Sn + vis_end) * Dn);
        f32x4* dst = (f32x4*)(out + ((size_t)b * T + MAXT) * Dn);
        const int base = c * 2048;              // 8 rows * 256 f32x4
        f32x4 v[8];
        int  e[8];
        bool p[8];
#pragma unroll
        for (int j = 0; j < 8; ++j) {
            e[j] = base + j * 256 + tid;
            p[j] = e[j] < tail4;
            if (p[j]) v[j] = __builtin_nontemporal_load(&src[e[j]]);
        }
#pragma unroll
        for (int j = 0; j < 8; ++j)
            if (p[j]) __builtin_nontemporal_store(v[j], &dst[e[j]]);
        return;
    }

    // ---- head: bitmap validity scan over 288 groups, then 4 gather rows ----
    __shared__ unsigned long long s_bm[BMW];
    __shared__ unsigned long long s_mask[5];
    __shared__ int s_wsum[5];
    __shared__ short s_gor[Gn];
    __shared__ char s_cnt[Gn];

    const int lane = tid & 63;
    const int w = tid >> 6;

    if (tid < BMW) s_bm[tid] = 0ull;
    __syncthreads();
    if (tid < Rn) {
        int r = rem[b * Rn + tid];
        if (r >= 0)
            atomicOr(&s_bm[r >> 6], 1ull << (r & 63));
    }
    __syncthreads();

    // validity counts: group tid, and group 256+tid for tid<32
    int cnt1 = 0;
    {
        const int4 gi = ((const int4*)idx)[b * Gn + tid];
        const int vv[4] = {gi.x, gi.y, gi.z, gi.w};
#pragma unroll
        for (int k = 0; k < Kn; ++k) {
            int v = vv[k];
            bool m = (v >= 0);
            int word = m ? (v >> 6) : 0;
            unsigned long long bit = (s_bm[word] >> (v & 63)) & 1ull;
            cnt1 += (m && !bit) ? 1 : 0;
        }
        s_cnt[tid] = (char)cnt1;
    }
    int cnt2 = 0;
    if (tid < Gn - 256) {
        const int4 gi = ((const int4*)idx)[b * Gn + 256 + tid];
        const int vv[4] = {gi.x, gi.y, gi.z, gi.w};
#pragma unroll
        for (int k = 0; k < Kn; ++k) {
            int v = vv[k];
            bool m = (v >= 0);
            int word = m ? (v >> 6) : 0;
            unsigned long long bit = (s_bm[word] >> (v & 63)) & 1ull;
            cnt2 += (m && !bit) ? 1 : 0;
        }
        s_cnt[256 + tid] = (char)cnt2;
    }

    unsigned long long m1 = __ballot(cnt1 > 0);
    if (lane == 0) { s_mask[w] = m1; s_wsum[w] = __popcll(m1); }
    if (w == 0) {
        unsigned long long m2 = __ballot(tid < Gn - 256 && cnt2 > 0);
        if (lane == 0) { s_mask[4] = m2; s_wsum[4] = __popcll(m2); }
    }
    __syncthreads();

    int pre[5], acc = 0;
#pragma unroll
    for (int i = 0; i < 5; ++i) { pre[i] = acc; acc += s_wsum[i]; }
    const int nvalid = acc;
    const int zcut = MAXT - nvalid;

    if (cnt1 > 0) {
        int rank = pre[w] + __popcll(s_mask[w] & ((1ull << lane) - 1ull));
        s_gor[rank] = (short)tid;
    }
    if (tid < Gn - 256 && cnt2 > 0) {
        int rank = pre[4] + __popcll(s_mask[4] & ((1ull << lane) - 1ull));
        s_gor[rank] = (short)(256 + tid);
    }
    __syncthreads();

    if (tid < 4) {
        int t = 4 * x + tid;
        att_out[(size_t)b * T + t] = (t >= zcut) ? 1.0f : 0.0f;
    }

    const int start = pr[b * 2];
    const int L = pr[b * 2 + 1] - start + 1;

#pragma unroll
    for (int i = 0; i < 4; ++i) {
        const int t = 4 * x + i;
        f32x4* outp = (f32x4*)(out + ((size_t)b * T + t) * Dn);
        if (t < zcut) {
            f32x4 z = {0.f, 0.f, 0.f, 0.f};
            __builtin_nontemporal_store(z, &outp[tid]);
            continue;
        }
        const int g = s_gor[t - zcut];
        const int4 gi = ((const int4*)idx)[b * Gn + g];
        const int vv[4] = {gi.x, gi.y, gi.z, gi.w};
        f32x4 a = {0.f, 0.f, 0.f, 0.f};
#pragma unroll
        for (int k = 0; k < Kn; ++k) {
            int v = vv[k];
            int wi = (v >= 0) ? v : v + L;     // reference: idx_w = idx>=0 ? idx : idx+L
            const f32x4* row = (const f32x4*)(hs + ((size_t)b * Sn + start + wi) * Dn);
            a += row[tid];
        }
        const int c = (int)s_cnt[g];
        const float scale = 1.0f / (float)((c > 1) ? c : 1);
        a *= scale;
        __builtin_nontemporal_store(a, &outp[tid]);
    }
}

extern "C" void kernel_launch(void* const* d_in, const int* in_sizes, int n_in,
                              void* d_out, int out_size, void* d_ws, size_t ws_size,
                              hipStream_t stream) {
    const float* hs  = (const float*)d_in[0];  // hidden_states (B,S,D) f32
    const int* attn  = (const int*)d_in[1];    // attention_mask (B,S)
    const int* pr    = (const int*)d_in[2];    // patch_range_list (B,2)
    const int* idx   = (const int*)d_in[3];    // patch_indices_list_list (B,G,K)
    const int* rem   = (const int*)d_in[4];    // remove_index_list_list (B,R)

    float* out = (float*)d_out;

    // out_size = B*T*D + B*T  =>  T
    const int T = out_size / (Bn * (Dn + 1));
    const int vis_end = Sn - (T - MAXT);

    float* att_out = out + (size_t)Bn * T * Dn;

    const int tailrows = T - MAXT;
    const int tail4 = tailrows * (Dn / 4);
    const int ntail = (tailrows + 7) / 8;      // 8-row chunks
    const int nheadblk = (MAXT + 3) / 4;       // 4 rows per block

    fused3_kernel<<<dim3(nheadblk + ntail, Bn), 256, 0, stream>>>(
        hs, idx, pr, rem, attn, out, att_out, vis_end, T, nheadblk, tail4, tailrows);
}

// Round 8
// 78.263 us; speedup vs baseline: 1.3234x; 1.3234x over previous
//
#include <hip/hip_runtime.h>
#include <hip/hip_bf16.h>

#define Bn 64
#define Sn 1452
#define Dn 1024
#define Gn 288
#define Kn 4
#define Rn 32
#define MAXT 300
#define BMW 18            // ceil(1152/64) bitmap words

typedef float f32x4 __attribute__((ext_vector_type(4)));

// Single fused kernel. R6 geometry (2 head rows/block, 4 tail rows/block),
// with the rem-bitmap validity check (cheap VALU) from R7.
__global__ void __launch_bounds__(256)
fused4_kernel(const float* __restrict__ hs,       // B*S*D
              const int* __restrict__ idx,        // B*G*K
              const int* __restrict__ pr,         // B*2
              const int* __restrict__ rem,        // B*R
              const int* __restrict__ attn,       // B*S
              float* __restrict__ out,            // B*T*D
              float* __restrict__ att_out,        // B*T
              int vis_end, int T, int nheadblk, int tail4, int tailrows) {
    const int x = blockIdx.x;
    const int b = blockIdx.y;
    const int tid = threadIdx.x;

    if (x >= nheadblk) {
        // ---- tail: 4 rows (16 KB) per block, 64 B/lane in flight ----
        const int c = x - nheadblk;
        if (tid < 4) {
            int tr = c * 4 + tid;
            if (tr < tailrows)
                att_out[(size_t)b * T + MAXT + tr] = (float)attn[b * Sn + vis_end + tr];
        }
        const f32x4* src = (const f32x4*)(hs + ((size_t)b * Sn + vis_end) * Dn);
        f32x4* dst = (f32x4*)(out + ((size_t)b * T + MAXT) * Dn);
        const int base = c * 1024;              // 4 rows * 256 f32x4
        f32x4 v0, v1, v2, v3;
        int e0 = base + 0 * 256 + tid;
        int e1 = base + 1 * 256 + tid;
        int e2 = base + 2 * 256 + tid;
        int e3 = base + 3 * 256 + tid;
        bool p0 = e0 < tail4, p1 = e1 < tail4, p2 = e2 < tail4, p3 = e3 < tail4;
        if (p0) v0 = __builtin_nontemporal_load(&src[e0]);
        if (p1) v1 = __builtin_nontemporal_load(&src[e1]);
        if (p2) v2 = __builtin_nontemporal_load(&src[e2]);
        if (p3) v3 = __builtin_nontemporal_load(&src[e3]);
        if (p0) __builtin_nontemporal_store(v0, &dst[e0]);
        if (p1) __builtin_nontemporal_store(v1, &dst[e1]);
        if (p2) __builtin_nontemporal_store(v2, &dst[e2]);
        if (p3) __builtin_nontemporal_store(v3, &dst[e3]);
        return;
    }

    // ---- head: bitmap validity scan over 288 groups, then 2 gather rows ----
    __shared__ unsigned long long s_bm[BMW];
    __shared__ unsigned long long s_mask[5];
    __shared__ int s_wsum[5];
    __shared__ short s_gor[Gn];
    __shared__ char s_cnt[Gn];

    const int lane = tid & 63;
    const int w = tid >> 6;

    if (tid < BMW) s_bm[tid] = 0ull;
    __syncthreads();
    if (tid < Rn) {
        int r = rem[b * Rn + tid];
        if (r >= 0)
            atomicOr(&s_bm[r >> 6], 1ull << (r & 63));
    }
    __syncthreads();

    // validity counts: group tid, and group 256+tid for tid<32
    int cnt1 = 0;
    {
        const int4 gi = ((const int4*)idx)[b * Gn + tid];
        const int vv[4] = {gi.x, gi.y, gi.z, gi.w};
#pragma unroll
        for (int k = 0; k < Kn; ++k) {
            int v = vv[k];
            bool m = (v >= 0);
            int word = m ? (v >> 6) : 0;
            unsigned long long bit = (s_bm[word] >> (v & 63)) & 1ull;
            cnt1 += (m && !bit) ? 1 : 0;
        }
        s_cnt[tid] = (char)cnt1;
    }
    int cnt2 = 0;
    if (tid < Gn - 256) {
        const int4 gi = ((const int4*)idx)[b * Gn + 256 + tid];
        const int vv[4] = {gi.x, gi.y, gi.z, gi.w};
#pragma unroll
        for (int k = 0; k < Kn; ++k) {
            int v = vv[k];
            bool m = (v >= 0);
            int word = m ? (v >> 6) : 0;
            unsigned long long bit = (s_bm[word] >> (v & 63)) & 1ull;
            cnt2 += (m && !bit) ? 1 : 0;
        }
        s_cnt[256 + tid] = (char)cnt2;
    }

    unsigned long long m1 = __ballot(cnt1 > 0);
    if (lane == 0) { s_mask[w] = m1; s_wsum[w] = __popcll(m1); }
    if (w == 0) {
        unsigned long long m2 = __ballot(tid < Gn - 256 && cnt2 > 0);
        if (lane == 0) { s_mask[4] = m2; s_wsum[4] = __popcll(m2); }
    }
    __syncthreads();

    int pre[5], acc = 0;
#pragma unroll
    for (int i = 0; i < 5; ++i) { pre[i] = acc; acc += s_wsum[i]; }
    const int nvalid = acc;
    const int zcut = MAXT - nvalid;

    if (cnt1 > 0) {
        int rank = pre[w] + __popcll(s_mask[w] & ((1ull << lane) - 1ull));
        s_gor[rank] = (short)tid;
    }
    if (tid < Gn - 256 && cnt2 > 0) {
        int rank = pre[4] + __popcll(s_mask[4] & ((1ull << lane) - 1ull));
        s_gor[rank] = (short)(256 + tid);
    }
    __syncthreads();

    if (tid < 2) {
        int t = 2 * x + tid;
        att_out[(size_t)b * T + t] = (t >= zcut) ? 1.0f : 0.0f;
    }

    const int start = pr[b * 2];
    const int L = pr[b * 2 + 1] - start + 1;

#pragma unroll
    for (int i = 0; i < 2; ++i) {
        const int t = 2 * x + i;
        f32x4* outp = (f32x4*)(out + ((size_t)b * T + t) * Dn);
        if (t < zcut) {
            f32x4 z = {0.f, 0.f, 0.f, 0.f};
            __builtin_nontemporal_store(z, &outp[tid]);
            continue;
        }
        const int g = s_gor[t - zcut];
        const int4 gi = ((const int4*)idx)[b * Gn + g];
        const int vv[4] = {gi.x, gi.y, gi.z, gi.w};
        f32x4 a = {0.f, 0.f, 0.f, 0.f};
#pragma unroll
        for (int k = 0; k < Kn; ++k) {
            int v = vv[k];
            int wi = (v >= 0) ? v : v + L;     // reference: idx_w = idx>=0 ? idx : idx+L
            const f32x4* row = (const f32x4*)(hs + ((size_t)b * Sn + start + wi) * Dn);
            a += row[tid];
        }
        const int c = (int)s_cnt[g];
        const float scale = 1.0f / (float)((c > 1) ? c : 1);
        a *= scale;
        __builtin_nontemporal_store(a, &outp[tid]);
    }
}

extern "C" void kernel_launch(void* const* d_in, const int* in_sizes, int n_in,
                              void* d_out, int out_size, void* d_ws, size_t ws_size,
                              hipStream_t stream) {
    const float* hs  = (const float*)d_in[0];  // hidden_states (B,S,D) f32
    const int* attn  = (const int*)d_in[1];    // attention_mask (B,S)
    const int* pr    = (const int*)d_in[2];    // patch_range_list (B,2)
    const int* idx   = (const int*)d_in[3];    // patch_indices_list_list (B,G,K)
    const int* rem   = (const int*)d_in[4];    // remove_index_list_list (B,R)

    float* out = (float*)d_out;

    // out_size = B*T*D + B*T  =>  T
    const int T = out_size / (Bn * (Dn + 1));
    const int vis_end = Sn - (T - MAXT);

    float* att_out = out + (size_t)Bn * T * Dn;

    const int tailrows = T - MAXT;
    const int tail4 = tailrows * (Dn / 4);
    const int ntail = (tailrows + 3) / 4;      // 4-row chunks
    const int nheadblk = (MAXT + 1) / 2;       // 2 rows per block

    fused4_kernel<<<dim3(nheadblk + ntail, Bn), 256, 0, stream>>>(
        hs, idx, pr, rem, attn, out, att_out, vis_end, T, nheadblk, tail4, tailrows);
}

// Round 9
// 77.422 us; speedup vs baseline: 1.3377x; 1.0109x over previous
//
#include <hip/hip_runtime.h>
#include <hip/hip_bf16.h>

#define Bn 64
#define Sn 1452
#define Dn 1024
#define Gn 288
#define Kn 4
#define Rn 32
#define MAXT 300
#define BMW 18            // ceil(1152/64) bitmap words

typedef float f32x4 __attribute__((ext_vector_type(4)));

// Single fused kernel. Head: 2 rows/block (R8 geometry). Tail: 8 rows/block
// (single-variable test of the R7 bundle's tail half).
__global__ void __launch_bounds__(256)
fused5_kernel(const float* __restrict__ hs,       // B*S*D
              const int* __restrict__ idx,        // B*G*K
              const int* __restrict__ pr,         // B*2
              const int* __restrict__ rem,        // B*R
              const int* __restrict__ attn,       // B*S
              float* __restrict__ out,            // B*T*D
              float* __restrict__ att_out,        // B*T
              int vis_end, int T, int nheadblk, int tail4, int tailrows) {
    const int x = blockIdx.x;
    const int b = blockIdx.y;
    const int tid = threadIdx.x;

    if (x >= nheadblk) {
        // ---- tail: 8 rows (32 KB) per block, 128 B/lane in flight ----
        const int c = x - nheadblk;
        if (tid < 8) {
            int tr = c * 8 + tid;
            if (tr < tailrows)
                att_out[(size_t)b * T + MAXT + tr] = (float)attn[b * Sn + vis_end + tr];
        }
        const f32x4* src = (const f32x4*)(hs + ((size_t)b * Sn + vis_end) * Dn);
        f32x4* dst = (f32x4*)(out + ((size_t)b * T + MAXT) * Dn);
        const int base = c * 2048;              // 8 rows * 256 f32x4
        f32x4 v0, v1, v2, v3, v4, v5, v6, v7;
        int e0 = base + 0 * 256 + tid;
        int e1 = base + 1 * 256 + tid;
        int e2 = base + 2 * 256 + tid;
        int e3 = base + 3 * 256 + tid;
        int e4 = base + 4 * 256 + tid;
        int e5 = base + 5 * 256 + tid;
        int e6 = base + 6 * 256 + tid;
        int e7 = base + 7 * 256 + tid;
        bool p0 = e0 < tail4, p1 = e1 < tail4, p2 = e2 < tail4, p3 = e3 < tail4;
        bool p4 = e4 < tail4, p5 = e5 < tail4, p6 = e6 < tail4, p7 = e7 < tail4;
        if (p0) v0 = __builtin_nontemporal_load(&src[e0]);
        if (p1) v1 = __builtin_nontemporal_load(&src[e1]);
        if (p2) v2 = __builtin_nontemporal_load(&src[e2]);
        if (p3) v3 = __builtin_nontemporal_load(&src[e3]);
        if (p4) v4 = __builtin_nontemporal_load(&src[e4]);
        if (p5) v5 = __builtin_nontemporal_load(&src[e5]);
        if (p6) v6 = __builtin_nontemporal_load(&src[e6]);
        if (p7) v7 = __builtin_nontemporal_load(&src[e7]);
        if (p0) __builtin_nontemporal_store(v0, &dst[e0]);
        if (p1) __builtin_nontemporal_store(v1, &dst[e1]);
        if (p2) __builtin_nontemporal_store(v2, &dst[e2]);
        if (p3) __builtin_nontemporal_store(v3, &dst[e3]);
        if (p4) __builtin_nontemporal_store(v4, &dst[e4]);
        if (p5) __builtin_nontemporal_store(v5, &dst[e5]);
        if (p6) __builtin_nontemporal_store(v6, &dst[e6]);
        if (p7) __builtin_nontemporal_store(v7, &dst[e7]);
        return;
    }

    // ---- head: bitmap validity scan over 288 groups, then 2 gather rows ----
    __shared__ unsigned long long s_bm[BMW];
    __shared__ unsigned long long s_mask[5];
    __shared__ int s_wsum[5];
    __shared__ short s_gor[Gn];
    __shared__ char s_cnt[Gn];

    const int lane = tid & 63;
    const int w = tid >> 6;

    if (tid < BMW) s_bm[tid] = 0ull;
    __syncthreads();
    if (tid < Rn) {
        int r = rem[b * Rn + tid];
        if (r >= 0)
            atomicOr(&s_bm[r >> 6], 1ull << (r & 63));
    }
    __syncthreads();

    // validity counts: group tid, and group 256+tid for tid<32
    int cnt1 = 0;
    {
        const int4 gi = ((const int4*)idx)[b * Gn + tid];
        const int vv[4] = {gi.x, gi.y, gi.z, gi.w};
#pragma unroll
        for (int k = 0; k < Kn; ++k) {
            int v = vv[k];
            bool m = (v >= 0);
            int word = m ? (v >> 6) : 0;
            unsigned long long bit = (s_bm[word] >> (v & 63)) & 1ull;
            cnt1 += (m && !bit) ? 1 : 0;
        }
        s_cnt[tid] = (char)cnt1;
    }
    int cnt2 = 0;
    if (tid < Gn - 256) {
        const int4 gi = ((const int4*)idx)[b * Gn + 256 + tid];
        const int vv[4] = {gi.x, gi.y, gi.z, gi.w};
#pragma unroll
        for (int k = 0; k < Kn; ++k) {
            int v = vv[k];
            bool m = (v >= 0);
            int word = m ? (v >> 6) : 0;
            unsigned long long bit = (s_bm[word] >> (v & 63)) & 1ull;
            cnt2 += (m && !bit) ? 1 : 0;
        }
        s_cnt[256 + tid] = (char)cnt2;
    }

    unsigned long long m1 = __ballot(cnt1 > 0);
    if (lane == 0) { s_mask[w] = m1; s_wsum[w] = __popcll(m1); }
    if (w == 0) {
        unsigned long long m2 = __ballot(tid < Gn - 256 && cnt2 > 0);
        if (lane == 0) { s_mask[4] = m2; s_wsum[4] = __popcll(m2); }
    }
    __syncthreads();

    int pre[5], acc = 0;
#pragma unroll
    for (int i = 0; i < 5; ++i) { pre[i] = acc; acc += s_wsum[i]; }
    const int nvalid = acc;
    const int zcut = MAXT - nvalid;

    if (cnt1 > 0) {
        int rank = pre[w] + __popcll(s_mask[w] & ((1ull << lane) - 1ull));
        s_gor[rank] = (short)tid;
    }
    if (tid < Gn - 256 && cnt2 > 0) {
        int rank = pre[4] + __popcll(s_mask[4] & ((1ull << lane) - 1ull));
        s_gor[rank] = (short)(256 + tid);
    }
    __syncthreads();

    if (tid < 2) {
        int t = 2 * x + tid;
        att_out[(size_t)b * T + t] = (t >= zcut) ? 1.0f : 0.0f;
    }

    const int start = pr[b * 2];
    const int L = pr[b * 2 + 1] - start + 1;

#pragma unroll
    for (int i = 0; i < 2; ++i) {
        const int t = 2 * x + i;
        f32x4* outp = (f32x4*)(out + ((size_t)b * T + t) * Dn);
        if (t < zcut) {
            f32x4 z = {0.f, 0.f, 0.f, 0.f};
            __builtin_nontemporal_store(z, &outp[tid]);
            continue;
        }
        const int g = s_gor[t - zcut];
        const int4 gi = ((const int4*)idx)[b * Gn + g];
        const int vv[4] = {gi.x, gi.y, gi.z, gi.w};
        f32x4 a = {0.f, 0.f, 0.f, 0.f};
#pragma unroll
        for (int k = 0; k < Kn; ++k) {
            int v = vv[k];
            int wi = (v >= 0) ? v : v + L;     // reference: idx_w = idx>=0 ? idx : idx+L
            const f32x4* row = (const f32x4*)(hs + ((size_t)b * Sn + start + wi) * Dn);
            a += row[tid];
        }
        const int c = (int)s_cnt[g];
        const float scale = 1.0f / (float)((c > 1) ? c : 1);
        a *= scale;
        __builtin_nontemporal_store(a, &outp[tid]);
    }
}

extern "C" void kernel_launch(void* const* d_in, const int* in_sizes, int n_in,
                              void* d_out, int out_size, void* d_ws, size_t ws_size,
                              hipStream_t stream) {
    const float* hs  = (const float*)d_in[0];  // hidden_states (B,S,D) f32
    const int* attn  = (const int*)d_in[1];    // attention_mask (B,S)
    const int* pr    = (const int*)d_in[2];    // patch_range_list (B,2)
    const int* idx   = (const int*)d_in[3];    // patch_indices_list_list (B,G,K)
    const int* rem   = (const int*)d_in[4];    // remove_index_list_list (B,R)

    float* out = (float*)d_out;

    // out_size = B*T*D + B*T  =>  T
    const int T = out_size / (Bn * (Dn + 1));
    const int vis_end = Sn - (T - MAXT);

    float* att_out = out + (size_t)Bn * T * Dn;

    const int tailrows = T - MAXT;
    const int tail4 = tailrows * (Dn / 4);
    const int ntail = (tailrows + 7) / 8;      // 8-row chunks
    const int nheadblk = (MAXT + 1) / 2;       // 2 rows per block

    fused5_kernel<<<dim3(nheadblk + ntail, Bn), 256, 0, stream>>>(
        hs, idx, pr, rem, attn, out, att_out, vis_end, T, nheadblk, tail4, tailrows);
}